// Round 15
// baseline (240.362 us; speedup 1.0000x reference)
//
#include <hip/hip_runtime.h>

// Problem constants (fixed by the reference)
static constexpr int N1  = 200000;
static constexpr int N2  = 40000;
static constexpr int N3  = 10000;
static constexpr int IND = 128;
static constexpr int HID = 256;
static constexpr int OUTD = 64;

using f32x4  = __attribute__((ext_vector_type(4))) float;
using bf16x8 = __attribute__((ext_vector_type(8))) short;  // 8 bf16 (4 VGPRs)

// round-to-nearest-even f32 -> bf16 (finite inputs)
__device__ __forceinline__ unsigned short f2bf(float f) {
    unsigned int u = __float_as_uint(f);
    u += 0x7FFFu + ((u >> 16) & 1u);
    return (unsigned short)(u >> 16);
}
__device__ __forceinline__ float bf2f(unsigned short u) {
    return __uint_as_float((unsigned int)u << 16);
}

static constexpr int NW1g = HID * 2 * IND / 4;    // 16,384 float4 groups
static constexpr int NW2g = OUTD * 2 * HID / 4;   //  8,192 float4 groups
static constexpr int NX_BIG   = N1 * IND / 8;     // 3,200,000 (8 floats/thr)
static constexpr int NX_SMALL = N2 * 32;          // 1,280,000 (4 floats/thr)

// ---------------------------------------------------------------------------
// prep: {x->bf16 convert | W1,W2 -> bf16}. (hist split back out: R14 showed
// the merged version ran slower than the two separately.)
// ---------------------------------------------------------------------------
__global__ __launch_bounds__(256) void prep_kernel(
    const float* __restrict__ x, unsigned short* __restrict__ xdst, int big,
    const float* __restrict__ W1l, const float* __restrict__ W1r,
    unsigned short* __restrict__ Wb1,
    const float* __restrict__ W2l, const float* __restrict__ W2r,
    unsigned short* __restrict__ W2b) {
    int i = blockIdx.x * blockDim.x + threadIdx.x;
    const int NX = big ? NX_BIG : NX_SMALL;
    if (i < NX) {
        if (big) {
            const float4* p = reinterpret_cast<const float4*>(x + (size_t)i * 8);
            float4 v0 = p[0], v1 = p[1];
            uint4 u;
            u.x = (unsigned int)f2bf(v0.x) | ((unsigned int)f2bf(v0.y) << 16);
            u.y = (unsigned int)f2bf(v0.z) | ((unsigned int)f2bf(v0.w) << 16);
            u.z = (unsigned int)f2bf(v1.x) | ((unsigned int)f2bf(v1.y) << 16);
            u.w = (unsigned int)f2bf(v1.z) | ((unsigned int)f2bf(v1.w) << 16);
            *reinterpret_cast<uint4*>(xdst + (size_t)i * 8) = u;
        } else {
            int row = i >> 5, c4 = (i & 31) * 4;
            float4 v = *reinterpret_cast<const float4*>(x + (size_t)row * IND + c4);
            unsigned int lo = (unsigned int)f2bf(v.x) | ((unsigned int)f2bf(v.y) << 16);
            unsigned int hi = (unsigned int)f2bf(v.z) | ((unsigned int)f2bf(v.w) << 16);
            *reinterpret_cast<uint2*>(xdst + (size_t)row * 256 + 128 + c4) =
                make_uint2(lo, hi);
        }
    } else if ((i -= NX) < NW1g) {
        int j = i >> 6, k4 = (i & 63) * 4;
        const float* src = (k4 < IND) ? (W1l + (size_t)j * IND + k4)
                                      : (W1r + (size_t)j * IND + (k4 - IND));
        float4 v = *reinterpret_cast<const float4*>(src);
        *reinterpret_cast<ushort4*>(Wb1 + (size_t)j * 256 + k4) =
            make_ushort4(f2bf(v.x), f2bf(v.y), f2bf(v.z), f2bf(v.w));
    } else if ((i -= NW1g) < NW2g) {
        int j = i >> 7, k4 = (i & 127) * 4;
        const float* src = (k4 < HID) ? (W2l + (size_t)j * HID + k4)
                                      : (W2r + (size_t)j * HID + (k4 - HID));
        float4 v = *reinterpret_cast<const float4*>(src);
        *reinterpret_cast<ushort4*>(W2b + (size_t)j * 512 + k4) =
            make_ushort4(f2bf(v.x), f2bf(v.y), f2bf(v.z), f2bf(v.w));
    }
}

// ---------------------------------------------------------------------------
// Fused histogram for both layers.
// ---------------------------------------------------------------------------
__global__ void hist_both_kernel(const int* __restrict__ dst1, int E1,
                                 const int* __restrict__ dst2, int E2,
                                 int* __restrict__ deg1,
                                 int* __restrict__ deg2) {
    int i = blockIdx.x * blockDim.x + threadIdx.x;
    if (i < E1) atomicAdd(&deg1[dst1[i]], 1);
    else if (i - E1 < E2) atomicAdd(&deg2[dst2[i - E1]], 1);
}

// ---------------------------------------------------------------------------
// Single-block fused exclusive scan of both deg arrays (proven ~5 us).
// ---------------------------------------------------------------------------
__device__ __forceinline__ int block_excl_scan(int s, int* wl) {
    __syncthreads();
    const int t = threadIdx.x, lane = t & 63, wid = t >> 6;
    int incl = s;
#pragma unroll
    for (int o = 1; o < 64; o <<= 1) {
        int u = __shfl_up(incl, o);
        if (lane >= o) incl += u;
    }
    if (lane == 63) wl[wid] = incl;
    __syncthreads();
    if (t < 16) {
        int v = wl[t], iv = v;
#pragma unroll
        for (int o = 1; o < 16; o <<= 1) {
            int u = __shfl_up(iv, o);
            if (t >= o) iv += u;
        }
        wl[t] = iv - v;
    }
    __syncthreads();
    return wl[wid] + incl - s;
}

template <int PER>
__device__ __forceinline__ void scan_seg(const int* __restrict__ deg,
                                         int* __restrict__ rs,
                                         int n4, int* wl) {
    const int t = threadIdx.x;
    int4 v[PER];
    int s = 0;
#pragma unroll
    for (int i = 0; i < PER; ++i) {
        int idx = t * PER + i;
        if (idx < n4) {
            v[i] = reinterpret_cast<const int4*>(deg)[idx];
            s += v[i].x + v[i].y + v[i].z + v[i].w;
        } else {
            v[i] = make_int4(0, 0, 0, 0);
        }
    }
    int run = block_excl_scan(s, wl);
#pragma unroll
    for (int i = 0; i < PER; ++i) {
        int idx = t * PER + i;
        if (idx < n4) {
            reinterpret_cast<int4*>(rs)[idx] =
                make_int4(run, run + v[i].x, run + v[i].x + v[i].y,
                          run + v[i].x + v[i].y + v[i].z);
            run += v[i].x + v[i].y + v[i].z + v[i].w;
        }
    }
}

__global__ __launch_bounds__(1024) void scan_fused_kernel(
    const int* __restrict__ deg1, int* __restrict__ rowstart1,
    const int* __restrict__ deg2, int* __restrict__ rowstart2) {
    __shared__ int wl[16];
    scan_seg<10>(deg1, rowstart1, N2 / 4, wl);
    scan_seg<3>(deg2, rowstart2, N3 / 4, wl);
}

// ---------------------------------------------------------------------------
// Fused CSR fill for both layers.
// ---------------------------------------------------------------------------
__global__ void fill_both_kernel(
    const int* __restrict__ src1, const int* __restrict__ dst1, int E1,
    const int* __restrict__ rowstart1, int* __restrict__ cursor1,
    int* __restrict__ csr1,
    const int* __restrict__ src2, const int* __restrict__ dst2, int E2,
    const int* __restrict__ rowstart2, int* __restrict__ cursor2,
    int* __restrict__ csr2) {
    int i = blockIdx.x * blockDim.x + threadIdx.x;
    if (i < E1) {
        int d = dst1[i];
        int p = atomicAdd(&cursor1[d], 1);
        csr1[rowstart1[d] + p] = src1[i];
    } else if (i - E1 < E2) {
        int j = i - E1;
        int d = dst2[j];
        int p = atomicAdd(&cursor2[d], 1);
        csr2[rowstart2[d] + p] = src2[j];
    }
}

// ---------------------------------------------------------------------------
// FUSED layer 1 (big path): gather-mean into LDS + MFMA GEMM.
// Block = 512 thr = 8 waves; tile 64 rows x 256 cols (grid 625, rows exact).
// Phase A: wave w gather-means nodes [blk+8w, blk+8w+8) into LDS Am
//   (stride 136 bf16: ds_read_b128 bank stride (4*l15)%32 -> 2-way = free).
// Phase B: 2Mx4N waves, wave tile 32x64, A half-0 from LDS, half-1 = xb rows.
// Eliminates the mean1b buffer (10 MB write + 20 MB re-read) and one launch.
// ---------------------------------------------------------------------------
__global__ __launch_bounds__(512) void fused1_kernel(
    const unsigned short* __restrict__ xb,
    const int* __restrict__ csr, const int* __restrict__ rowstart,
    const int* __restrict__ deg,
    const unsigned short* __restrict__ Wb, const float* __restrict__ b1,
    unsigned short* __restrict__ hb) {
    constexpr int LST = 136;                    // bf16 elems per LDS row
    __shared__ unsigned short Am[64 * LST];     // 17,408 B
    const int t    = threadIdx.x;
    const int w    = t >> 6;                    // 0..7
    const int lane = t & 63;
    const int blk  = blockIdx.x * 64;

    // ---- phase A: gather-mean for 8 rows per wave ----
    const unsigned short* __restrict__ xcol = xb + lane * 2;
#pragma unroll 1
    for (int r = w * 8; r < w * 8 + 8; ++r) {
        const int node = blk + r;
        const int beg = rowstart[node];
        const int n   = deg[node];
        float a0 = 0.f, a1 = 0.f, b0 = 0.f, b1v = 0.f;
        float c0 = 0.f, c1 = 0.f, d0 = 0.f, d1v = 0.f;
        int e = 0;
        for (; e + 3 < n; e += 4) {
            int s0 = csr[beg + e],     s1 = csr[beg + e + 1];
            int s2 = csr[beg + e + 2], s3 = csr[beg + e + 3];
            unsigned int v0 = *reinterpret_cast<const unsigned int*>(xcol + (size_t)s0 * IND);
            unsigned int v1 = *reinterpret_cast<const unsigned int*>(xcol + (size_t)s1 * IND);
            unsigned int v2 = *reinterpret_cast<const unsigned int*>(xcol + (size_t)s2 * IND);
            unsigned int v3 = *reinterpret_cast<const unsigned int*>(xcol + (size_t)s3 * IND);
            a0 += bf2f((unsigned short)v0); a1  += bf2f((unsigned short)(v0 >> 16));
            b0 += bf2f((unsigned short)v1); b1v += bf2f((unsigned short)(v1 >> 16));
            c0 += bf2f((unsigned short)v2); c1  += bf2f((unsigned short)(v2 >> 16));
            d0 += bf2f((unsigned short)v3); d1v += bf2f((unsigned short)(v3 >> 16));
        }
        for (; e < n; ++e) {
            int s0 = csr[beg + e];
            unsigned int v0 = *reinterpret_cast<const unsigned int*>(xcol + (size_t)s0 * IND);
            a0 += bf2f((unsigned short)v0); a1 += bf2f((unsigned short)(v0 >> 16));
        }
        const float inv = (n > 0) ? 1.0f / (float)n : 0.0f;
        const float m0 = ((a0 + b0) + (c0 + d0)) * inv;
        const float m1 = ((a1 + b1v) + (c1 + d1v)) * inv;
        unsigned int packed = (unsigned int)f2bf(m0) | ((unsigned int)f2bf(m1) << 16);
        *reinterpret_cast<unsigned int*>(&Am[r * LST + lane * 2]) = packed;
    }
    __syncthreads();

    // ---- phase B: MFMA 64x256 ----
    const int l15 = lane & 15;
    const int kh  = lane >> 4;                 // 0..3
    const int wm  = w >> 2;                    // 0..1
    const int wn  = w & 3;                     // 0..3
    const int lr0 = wm * 32;                   // local row base
    const int col0 = wn * 64;

    f32x4 acc[2][4];
#pragma unroll
    for (int m = 0; m < 2; ++m)
#pragma unroll
        for (int n = 0; n < 4; ++n)
            acc[m][n] = (f32x4){0.f, 0.f, 0.f, 0.f};

#pragma unroll
    for (int ks = 0; ks < 8; ++ks) {
        const int k0 = (ks & 3) * 32 + kh * 8;
        bf16x8 a[2], b[4];
#pragma unroll
        for (int m = 0; m < 2; ++m) {
            if (ks < 4)
                a[m] = *reinterpret_cast<const bf16x8*>(
                    &Am[(lr0 + m * 16 + l15) * LST + k0]);
            else
                a[m] = *reinterpret_cast<const bf16x8*>(
                    xb + (size_t)(blk + lr0 + m * 16 + l15) * IND + k0);
        }
#pragma unroll
        for (int n = 0; n < 4; ++n)
            b[n] = *reinterpret_cast<const bf16x8*>(
                Wb + (size_t)(col0 + n * 16 + l15) * 256 + ks * 32 + kh * 8);
#pragma unroll
        for (int m = 0; m < 2; ++m)
#pragma unroll
            for (int n = 0; n < 4; ++n)
                acc[m][n] = __builtin_amdgcn_mfma_f32_16x16x32_bf16(
                    a[m], b[n], acc[m][n], 0, 0, 0);
    }

#pragma unroll
    for (int m = 0; m < 2; ++m) {
        const int r0 = blk + lr0 + m * 16 + kh * 4;
#pragma unroll
        for (int n = 0; n < 4; ++n) {
            const int c = col0 + n * 16 + l15;
            const float bias = b1[c];
#pragma unroll
            for (int j = 0; j < 4; ++j)
                hb[(size_t)(r0 + j) * HID + c] =
                    f2bf(fmaxf(acc[m][n][j] + bias, 0.0f));
        }
    }
}

// ---------------------------------------------------------------------------
// OLD (small-ws) path gather-mean layer 1: fp32 gather -> A1b cols [0,128).
// ---------------------------------------------------------------------------
__global__ __launch_bounds__(256) void gather1_kernel(
    const float* __restrict__ x, const int* __restrict__ csr,
    const int* __restrict__ rowstart, const int* __restrict__ deg,
    unsigned short* __restrict__ A1b) {
    const int node = blockIdx.x * 4 + (threadIdx.x >> 6);
    const int lane = threadIdx.x & 63;
    const int beg = rowstart[node];
    const int n   = deg[node];
    float2 acc0 = make_float2(0.f, 0.f), acc1 = make_float2(0.f, 0.f);
    int e = 0;
    for (; e + 1 < n; e += 2) {
        int s0 = csr[beg + e];
        int s1 = csr[beg + e + 1];
        float2 v0 = *reinterpret_cast<const float2*>(x + (size_t)s0 * IND + lane * 2);
        float2 v1 = *reinterpret_cast<const float2*>(x + (size_t)s1 * IND + lane * 2);
        acc0.x += v0.x; acc0.y += v0.y;
        acc1.x += v1.x; acc1.y += v1.y;
    }
    if (e < n) {
        int s0 = csr[beg + e];
        float2 v0 = *reinterpret_cast<const float2*>(x + (size_t)s0 * IND + lane * 2);
        acc0.x += v0.x; acc0.y += v0.y;
    }
    const float inv = (n > 0) ? 1.0f / (float)n : 0.0f;
    unsigned int packed = (unsigned int)f2bf((acc0.x + acc1.x) * inv)
                        | ((unsigned int)f2bf((acc0.y + acc1.y) * inv) << 16);
    *reinterpret_cast<unsigned int*>(A1b + (size_t)node * 256 + lane * 2) = packed;
}

// ---------------------------------------------------------------------------
// OLD (small-ws) layer-1 dense GEMM on MFMA, two-pointer A.
// ---------------------------------------------------------------------------
__global__ __launch_bounds__(256) void sage1_kernel(
    const unsigned short* __restrict__ Am, int sM,
    const unsigned short* __restrict__ Ax, int sX,
    const unsigned short* __restrict__ Wb,
    const float* __restrict__ b1,
    unsigned short* __restrict__ hb) {
    const int t    = threadIdx.x;
    const int wave = t >> 6;
    const int lane = t & 63;
    const int l15  = lane & 15;
    const int kh   = lane >> 4;
    const int wm   = wave >> 1;
    const int wn   = wave & 1;
    const int row0 = blockIdx.x * 64 + wm * 32;
    const int col0 = blockIdx.y * 128 + wn * 64;

    f32x4 acc[2][4];
#pragma unroll
    for (int m = 0; m < 2; ++m)
#pragma unroll
        for (int n = 0; n < 4; ++n)
            acc[m][n] = (f32x4){0.f, 0.f, 0.f, 0.f};

#pragma unroll
    for (int ks = 0; ks < 8; ++ks) {
        const unsigned short* __restrict__ Ab = (ks < 4) ? Am : Ax;
        const int sA = (ks < 4) ? sM : sX;
        const int k0 = (ks & 3) * 32 + kh * 8;
        bf16x8 a[2], b[4];
#pragma unroll
        for (int m = 0; m < 2; ++m)
            a[m] = *reinterpret_cast<const bf16x8*>(
                Ab + (size_t)(row0 + m * 16 + l15) * sA + k0);
#pragma unroll
        for (int n = 0; n < 4; ++n)
            b[n] = *reinterpret_cast<const bf16x8*>(
                Wb + (size_t)(col0 + n * 16 + l15) * 256 + ks * 32 + kh * 8);
#pragma unroll
        for (int m = 0; m < 2; ++m)
#pragma unroll
            for (int n = 0; n < 4; ++n)
                acc[m][n] = __builtin_amdgcn_mfma_f32_16x16x32_bf16(
                    a[m], b[n], acc[m][n], 0, 0, 0);
    }

#pragma unroll
    for (int m = 0; m < 2; ++m) {
        const int r0 = row0 + m * 16 + kh * 4;
#pragma unroll
        for (int n = 0; n < 4; ++n) {
            const int c = col0 + n * 16 + l15;
            const float bias = b1[c];
#pragma unroll
            for (int j = 0; j < 4; ++j)
                hb[(size_t)(r0 + j) * HID + c] =
                    f2bf(fmaxf(acc[m][n][j] + bias, 0.0f));
        }
    }
}

// ---------------------------------------------------------------------------
// Gather-mean layer 2 (bf16 in, f32 accum, bf16 out, 4-edge unroll).
// ---------------------------------------------------------------------------
__global__ __launch_bounds__(256) void gather2_kernel(
    const unsigned short* __restrict__ hb, const int* __restrict__ csr,
    const int* __restrict__ rowstart, const int* __restrict__ deg,
    unsigned short* __restrict__ meanb) {
    const int node = blockIdx.x * 4 + (threadIdx.x >> 6);
    const int lane = threadIdx.x & 63;
    const int beg = rowstart[node];
    const int n   = deg[node];
    const unsigned short* __restrict__ hcol = hb + lane * 4;
    float acc0 = 0.f, acc1 = 0.f, acc2 = 0.f, acc3 = 0.f;
    int e = 0;
    for (; e + 3 < n; e += 4) {
        int s0 = csr[beg + e],     s1 = csr[beg + e + 1];
        int s2 = csr[beg + e + 2], s3 = csr[beg + e + 3];
        ushort4 v0 = *reinterpret_cast<const ushort4*>(hcol + (size_t)s0 * HID);
        ushort4 v1 = *reinterpret_cast<const ushort4*>(hcol + (size_t)s1 * HID);
        ushort4 v2 = *reinterpret_cast<const ushort4*>(hcol + (size_t)s2 * HID);
        ushort4 v3 = *reinterpret_cast<const ushort4*>(hcol + (size_t)s3 * HID);
        acc0 += (bf2f(v0.x) + bf2f(v1.x)) + (bf2f(v2.x) + bf2f(v3.x));
        acc1 += (bf2f(v0.y) + bf2f(v1.y)) + (bf2f(v2.y) + bf2f(v3.y));
        acc2 += (bf2f(v0.z) + bf2f(v1.z)) + (bf2f(v2.z) + bf2f(v3.z));
        acc3 += (bf2f(v0.w) + bf2f(v1.w)) + (bf2f(v2.w) + bf2f(v3.w));
    }
    for (; e < n; ++e) {
        int s0 = csr[beg + e];
        ushort4 v0 = *reinterpret_cast<const ushort4*>(hcol + (size_t)s0 * HID);
        acc0 += bf2f(v0.x); acc1 += bf2f(v0.y);
        acc2 += bf2f(v0.z); acc3 += bf2f(v0.w);
    }
    const float inv = (n > 0) ? 1.0f / (float)n : 0.0f;
    unsigned int lo = (unsigned int)f2bf(acc0 * inv)
                    | ((unsigned int)f2bf(acc1 * inv) << 16);
    unsigned int hi = (unsigned int)f2bf(acc2 * inv)
                    | ((unsigned int)f2bf(acc3 * inv) << 16);
    *reinterpret_cast<uint2*>(meanb + (size_t)node * HID + lane * 4) =
        make_uint2(lo, hi);
}

// ---------------------------------------------------------------------------
// Layer-2 dense GEMM on MFMA + in-register log_softmax.
// ---------------------------------------------------------------------------
__global__ __launch_bounds__(256) void sage2_kernel(
    const unsigned short* __restrict__ hb,
    const unsigned short* __restrict__ meanb,
    const unsigned short* __restrict__ Wb,
    const float* __restrict__ b2,
    float* __restrict__ out) {
    const int t    = threadIdx.x;
    const int wave = t >> 6;
    const int lane = t & 63;
    const int l15  = lane & 15;
    const int kh   = lane >> 4;
    const int row0 = blockIdx.x * 64 + wave * 16;
    const int arow = min(row0 + l15, N3 - 1);   // clamp loads; stores guarded

    f32x4 acc[4];
#pragma unroll
    for (int n = 0; n < 4; ++n) acc[n] = (f32x4){0.f, 0.f, 0.f, 0.f};

#pragma unroll
    for (int half = 0; half < 2; ++half) {
        const unsigned short* __restrict__ A = half ? hb : meanb;
#pragma unroll
        for (int ks = 0; ks < 8; ++ks) {
            const int k0 = ks * 32 + kh * 8;
            bf16x8 a = *reinterpret_cast<const bf16x8*>(
                A + (size_t)arow * HID + k0);
            bf16x8 b[4];
#pragma unroll
            for (int n = 0; n < 4; ++n)
                b[n] = *reinterpret_cast<const bf16x8*>(
                    Wb + (size_t)(n * 16 + l15) * 512 + half * 256 + k0);
#pragma unroll
            for (int n = 0; n < 4; ++n)
                acc[n] = __builtin_amdgcn_mfma_f32_16x16x32_bf16(
                    a, b[n], acc[n], 0, 0, 0);
        }
    }

    float v[4][4];
#pragma unroll
    for (int n = 0; n < 4; ++n) {
        const float bn = b2[n * 16 + l15];
#pragma unroll
        for (int j = 0; j < 4; ++j) v[n][j] = acc[n][j] + bn;
    }

#pragma unroll
    for (int j = 0; j < 4; ++j) {
        float mx = fmaxf(fmaxf(v[0][j], v[1][j]), fmaxf(v[2][j], v[3][j]));
#pragma unroll
        for (int o = 1; o <= 8; o <<= 1) mx = fmaxf(mx, __shfl_xor(mx, o));
        float sm = 0.f;
#pragma unroll
        for (int n = 0; n < 4; ++n) sm += __expf(v[n][j] - mx);
#pragma unroll
        for (int o = 1; o <= 8; o <<= 1) sm += __shfl_xor(sm, o);
        const float lse = mx + __logf(sm);
        const int r = row0 + kh * 4 + j;
        if (r < N3) {
#pragma unroll
            for (int n = 0; n < 4; ++n)
                out[(size_t)r * OUTD + n * 16 + l15] = v[n][j] - lse;
        }
    }
}

// ---------------------------------------------------------------------------
extern "C" void kernel_launch(void* const* d_in, const int* in_sizes, int n_in,
                              void* d_out, int out_size, void* d_ws, size_t ws_size,
                              hipStream_t stream) {
    const float* x    = (const float*)d_in[0];
    const int*   src1 = (const int*)d_in[1];
    const int*   dst1 = (const int*)d_in[2];
    const int*   src2 = (const int*)d_in[3];
    const int*   dst2 = (const int*)d_in[4];
    const float* W1l  = (const float*)d_in[7];
    const float* W1r  = (const float*)d_in[8];
    const float* b1   = (const float*)d_in[9];
    const float* W2l  = (const float*)d_in[10];
    const float* W2r  = (const float*)d_in[11];
    const float* b2   = (const float*)d_in[12];
    float* out = (float*)d_out;

    const int E1 = in_sizes[1];
    const int E2 = in_sizes[3];

    static constexpr size_t NEED_NEW = 85916608;
    const bool big = ws_size >= NEED_NEW;

    char* ws = (char*)d_ws;
    unsigned short *mean2b, *hb, *xb = nullptr, *A1b = nullptr;
    unsigned short *W2b, *Wb1;
    int *csr1, *csr2, *deg1, *cursor1, *deg2, *cursor2, *rowstart1, *rowstart2;
    char* z0;

    if (big) {
        mean2b   = (unsigned short*)(ws + 0);           // 5,120,000 (scratch)
        hb       = (unsigned short*)(ws + 10240000);    // 20,480,000
        xb       = (unsigned short*)(ws + 30720000);    // 51,200,000
        csr1     = (int*)(ws + 81920000);               //  2,560,000
        csr2     = (int*)(ws + 84480000);               //    640,000
        deg1     = (int*)(ws + 85120000);               //    160,000
        cursor1  = (int*)(ws + 85280000);               //    160,000
        deg2     = (int*)(ws + 85440000);               //     40,000
        cursor2  = (int*)(ws + 85480000);               //     40,000
        rowstart1= (int*)(ws + 85520000);
        rowstart2= (int*)(ws + 85680000);
        W2b      = (unsigned short*)(ws + 85720000);
        Wb1      = (unsigned short*)(ws + 85785536);    // end 85,916,608
        z0 = ws + 85120000;
    } else {
        A1b      = (unsigned short*)(ws + 0);           // 20,480,000
        mean2b   = (unsigned short*)(ws + 0);
        hb       = (unsigned short*)(ws + 20480000);    // 20,480,000
        csr1     = (int*)(ws + 40960000);               //  2,560,000
        csr2     = (int*)(ws + 43520000);               //    640,000
        deg1     = (int*)(ws + 44160000);
        cursor1  = (int*)(ws + 44320000);
        deg2     = (int*)(ws + 44480000);
        cursor2  = (int*)(ws + 44520000);
        rowstart1= (int*)(ws + 44560000);
        rowstart2= (int*)(ws + 44720000);
        W2b      = (unsigned short*)(ws + 44760000);
        Wb1      = (unsigned short*)(ws + 44825536);    // end 44,956,608
        z0 = ws + 44160000;
    }

    // zero deg1|cursor1|deg2|cursor2 (contiguous 400,000 B)
    hipMemsetAsync(z0, 0, 400000, stream);

    // ---- prep: convert + weights ----
    {
        const int NX = big ? NX_BIG : NX_SMALL;
        const int total = NX + NW1g + NW2g;
        prep_kernel<<<(total + 255) / 256, 256, 0, stream>>>(
            x, big ? xb : A1b, (int)big,
            W1l, W1r, Wb1, W2l, W2r, W2b);
    }

    // ---- CSR build ----
    {
        int tot = E1 + E2;
        hist_both_kernel<<<(tot + 255) / 256, 256, 0, stream>>>(
            dst1, E1, dst2, E2, deg1, deg2);
        scan_fused_kernel<<<1, 1024, 0, stream>>>(deg1, rowstart1,
                                                  deg2, rowstart2);
        fill_both_kernel<<<(tot + 255) / 256, 256, 0, stream>>>(
            src1, dst1, E1, rowstart1, cursor1, csr1,
            src2, dst2, E2, rowstart2, cursor2, csr2);
    }

    // ---- layer 1 ----
    if (big) {
        fused1_kernel<<<N2 / 64, 512, 0, stream>>>(xb, csr1, rowstart1, deg1,
                                                   Wb1, b1, hb);
    } else {
        gather1_kernel<<<N2 / 4, 256, 0, stream>>>(x, csr1, rowstart1, deg1, A1b);
        dim3 grid(N2 / 64, HID / 128);
        sage1_kernel<<<grid, 256, 0, stream>>>(A1b, HID, A1b + 128, HID, Wb1,
                                               b1, hb);
    }

    // ---- layer 2: gather-mean + MFMA dense + log_softmax ----
    gather2_kernel<<<N3 / 4, 256, 0, stream>>>(hb, csr2, rowstart2, deg2, mean2b);
    sage2_kernel<<<(N3 + 63) / 64, 256, 0, stream>>>(hb, mean2b, W2b, b2, out);
}

// Round 16
// 208.758 us; speedup vs baseline: 1.1514x; 1.1514x over previous
//
#include <hip/hip_runtime.h>

// Problem constants (fixed by the reference)
static constexpr int N1  = 200000;
static constexpr int N2  = 40000;
static constexpr int N3  = 10000;
static constexpr int IND = 128;
static constexpr int HID = 256;
static constexpr int OUTD = 64;

using f32x4  = __attribute__((ext_vector_type(4))) float;
using bf16x8 = __attribute__((ext_vector_type(8))) short;  // 8 bf16 (4 VGPRs)

// round-to-nearest-even f32 -> bf16 (finite inputs)
__device__ __forceinline__ unsigned short f2bf(float f) {
    unsigned int u = __float_as_uint(f);
    u += 0x7FFFu + ((u >> 16) & 1u);
    return (unsigned short)(u >> 16);
}
__device__ __forceinline__ float bf2f(unsigned short u) {
    return __uint_as_float((unsigned int)u << 16);
}

// ---------------------------------------------------------------------------
// Fused prep: zero {deg|cursor} block + W1->bf16 + W2->bf16 + x->bf16.
// (R12 configuration — proven best at 208 us. R13's last-block-done scan
// regressed 7x via per-block __threadfence; R15's gather+GEMM fusion
// regressed via gather-TLP collapse. Phases keep their own grids.)
// ---------------------------------------------------------------------------
static constexpr int NZ4  = 400000 / 16;          // 25,000 int4
static constexpr int NW1g = HID * 2 * IND / 4;    // 16,384 groups
static constexpr int NW2g = OUTD * 2 * HID / 4;   //  8,192 groups
static constexpr int NX_BIG   = N1 * IND / 8;     // 3,200,000
static constexpr int NX_SMALL = N2 * 32;          // 1,280,000

__global__ void prep_kernel(const float* __restrict__ x,
                            unsigned short* __restrict__ xdst, int big,
                            int4* __restrict__ z0,
                            const float* __restrict__ W1l,
                            const float* __restrict__ W1r,
                            unsigned short* __restrict__ Wb1,
                            const float* __restrict__ W2l,
                            const float* __restrict__ W2r,
                            unsigned short* __restrict__ W2b) {
    int i = blockIdx.x * blockDim.x + threadIdx.x;
    const int NX = big ? NX_BIG : NX_SMALL;
    if (i < NX) {
        if (big) {
            const float4* p = reinterpret_cast<const float4*>(x + (size_t)i * 8);
            float4 v0 = p[0], v1 = p[1];
            uint4 u;
            u.x = (unsigned int)f2bf(v0.x) | ((unsigned int)f2bf(v0.y) << 16);
            u.y = (unsigned int)f2bf(v0.z) | ((unsigned int)f2bf(v0.w) << 16);
            u.z = (unsigned int)f2bf(v1.x) | ((unsigned int)f2bf(v1.y) << 16);
            u.w = (unsigned int)f2bf(v1.z) | ((unsigned int)f2bf(v1.w) << 16);
            *reinterpret_cast<uint4*>(xdst + (size_t)i * 8) = u;
        } else {
            int row = i >> 5, c4 = (i & 31) * 4;
            float4 v = *reinterpret_cast<const float4*>(x + (size_t)row * IND + c4);
            unsigned int lo = (unsigned int)f2bf(v.x) | ((unsigned int)f2bf(v.y) << 16);
            unsigned int hi = (unsigned int)f2bf(v.z) | ((unsigned int)f2bf(v.w) << 16);
            *reinterpret_cast<uint2*>(xdst + (size_t)row * 256 + 128 + c4) =
                make_uint2(lo, hi);
        }
        return;
    }
    i -= NX;
    if (i < NZ4) { z0[i] = make_int4(0, 0, 0, 0); return; }
    i -= NZ4;
    if (i < NW1g) {
        int j = i >> 6, k4 = (i & 63) * 4;
        const float* src = (k4 < IND) ? (W1l + (size_t)j * IND + k4)
                                      : (W1r + (size_t)j * IND + (k4 - IND));
        float4 v = *reinterpret_cast<const float4*>(src);
        ushort4 o = make_ushort4(f2bf(v.x), f2bf(v.y), f2bf(v.z), f2bf(v.w));
        *reinterpret_cast<ushort4*>(Wb1 + (size_t)j * 256 + k4) = o;
        return;
    }
    i -= NW1g;
    if (i < NW2g) {
        int j = i >> 7, k4 = (i & 127) * 4;
        const float* src = (k4 < HID) ? (W2l + (size_t)j * HID + k4)
                                      : (W2r + (size_t)j * HID + (k4 - HID));
        float4 v = *reinterpret_cast<const float4*>(src);
        ushort4 o = make_ushort4(f2bf(v.x), f2bf(v.y), f2bf(v.z), f2bf(v.w));
        *reinterpret_cast<ushort4*>(W2b + (size_t)j * 512 + k4) = o;
    }
}

// ---------------------------------------------------------------------------
// Fused histogram for both layers.
// ---------------------------------------------------------------------------
__global__ void hist_both_kernel(const int* __restrict__ dst1, int E1,
                                 const int* __restrict__ dst2, int E2,
                                 int* __restrict__ deg1,
                                 int* __restrict__ deg2) {
    int i = blockIdx.x * blockDim.x + threadIdx.x;
    if (i < E1) atomicAdd(&deg1[dst1[i]], 1);
    else if (i - E1 < E2) atomicAdd(&deg2[dst2[i - E1]], 1);
}

// ---------------------------------------------------------------------------
// Single-block fused exclusive scan of both deg arrays (int4 + two-level
// shfl scan). 1024 threads, 16 waves. (~5 us; proven in R11/R12.)
// ---------------------------------------------------------------------------
__device__ __forceinline__ int block_excl_scan(int s, int* wl) {
    __syncthreads();                       // protect wl reuse across calls
    const int t = threadIdx.x, lane = t & 63, wid = t >> 6;
    int incl = s;
#pragma unroll
    for (int o = 1; o < 64; o <<= 1) {
        int u = __shfl_up(incl, o);
        if (lane >= o) incl += u;
    }
    if (lane == 63) wl[wid] = incl;
    __syncthreads();
    if (t < 16) {
        int v = wl[t], iv = v;
#pragma unroll
        for (int o = 1; o < 16; o <<= 1) {
            int u = __shfl_up(iv, o);
            if (t >= o) iv += u;
        }
        wl[t] = iv - v;                    // exclusive wave prefix
    }
    __syncthreads();
    return wl[wid] + incl - s;
}

template <int PER>
__device__ __forceinline__ void scan_seg(const int* __restrict__ deg,
                                         int* __restrict__ rs,
                                         int n4, int* wl) {
    const int t = threadIdx.x;
    int4 v[PER];
    int s = 0;
#pragma unroll
    for (int i = 0; i < PER; ++i) {
        int idx = t * PER + i;
        if (idx < n4) {
            v[i] = reinterpret_cast<const int4*>(deg)[idx];
            s += v[i].x + v[i].y + v[i].z + v[i].w;
        } else {
            v[i] = make_int4(0, 0, 0, 0);
        }
    }
    int run = block_excl_scan(s, wl);
#pragma unroll
    for (int i = 0; i < PER; ++i) {
        int idx = t * PER + i;
        if (idx < n4) {
            reinterpret_cast<int4*>(rs)[idx] =
                make_int4(run, run + v[i].x, run + v[i].x + v[i].y,
                          run + v[i].x + v[i].y + v[i].z);
            run += v[i].x + v[i].y + v[i].z + v[i].w;
        }
    }
}

__global__ __launch_bounds__(1024) void scan_fused_kernel(
    const int* __restrict__ deg1, int* __restrict__ rowstart1,
    const int* __restrict__ deg2, int* __restrict__ rowstart2) {
    __shared__ int wl[16];
    scan_seg<10>(deg1, rowstart1, N2 / 4, wl);   // 10,000 int4
    scan_seg<3>(deg2, rowstart2, N3 / 4, wl);    //  2,500 int4
}

// ---------------------------------------------------------------------------
// Fused CSR fill for both layers.
// ---------------------------------------------------------------------------
__global__ void fill_both_kernel(
    const int* __restrict__ src1, const int* __restrict__ dst1, int E1,
    const int* __restrict__ rowstart1, int* __restrict__ cursor1,
    int* __restrict__ csr1,
    const int* __restrict__ src2, const int* __restrict__ dst2, int E2,
    const int* __restrict__ rowstart2, int* __restrict__ cursor2,
    int* __restrict__ csr2) {
    int i = blockIdx.x * blockDim.x + threadIdx.x;
    if (i < E1) {
        int d = dst1[i];
        int p = atomicAdd(&cursor1[d], 1);
        csr1[rowstart1[d] + p] = src1[i];
    } else if (i - E1 < E2) {
        int j = i - E1;
        int d = dst2[j];
        int p = atomicAdd(&cursor2[d], 1);
        csr2[rowstart2[d] + p] = src2[j];
    }
}

// ---------------------------------------------------------------------------
// NEW path gather-mean layer 1 (bf16 gather, 4-edge unroll). One wave per
// node (40,000 waves of TLP — do NOT fuse into the GEMM; R15 lesson).
// ---------------------------------------------------------------------------
__global__ __launch_bounds__(256) void gather1b_kernel(
    const unsigned short* __restrict__ xb, const int* __restrict__ csr,
    const int* __restrict__ rowstart, const int* __restrict__ deg,
    unsigned short* __restrict__ meanb) {
    const int node = blockIdx.x * 4 + (threadIdx.x >> 6);
    const int lane = threadIdx.x & 63;
    const int beg = rowstart[node];
    const int n   = deg[node];
    const unsigned short* __restrict__ xcol = xb + lane * 2;
    float a0 = 0.f, a1 = 0.f, b0 = 0.f, b1 = 0.f;
    float c0 = 0.f, c1 = 0.f, d0 = 0.f, d1 = 0.f;
    int e = 0;
    for (; e + 3 < n; e += 4) {
        int s0 = csr[beg + e],     s1 = csr[beg + e + 1];
        int s2 = csr[beg + e + 2], s3 = csr[beg + e + 3];
        unsigned int v0 = *reinterpret_cast<const unsigned int*>(xcol + (size_t)s0 * IND);
        unsigned int v1 = *reinterpret_cast<const unsigned int*>(xcol + (size_t)s1 * IND);
        unsigned int v2 = *reinterpret_cast<const unsigned int*>(xcol + (size_t)s2 * IND);
        unsigned int v3 = *reinterpret_cast<const unsigned int*>(xcol + (size_t)s3 * IND);
        a0 += bf2f((unsigned short)v0); a1 += bf2f((unsigned short)(v0 >> 16));
        b0 += bf2f((unsigned short)v1); b1 += bf2f((unsigned short)(v1 >> 16));
        c0 += bf2f((unsigned short)v2); c1 += bf2f((unsigned short)(v2 >> 16));
        d0 += bf2f((unsigned short)v3); d1 += bf2f((unsigned short)(v3 >> 16));
    }
    for (; e < n; ++e) {
        int s0 = csr[beg + e];
        unsigned int v0 = *reinterpret_cast<const unsigned int*>(xcol + (size_t)s0 * IND);
        a0 += bf2f((unsigned short)v0); a1 += bf2f((unsigned short)(v0 >> 16));
    }
    const float inv = (n > 0) ? 1.0f / (float)n : 0.0f;
    const float m0 = ((a0 + b0) + (c0 + d0)) * inv;
    const float m1 = ((a1 + b1) + (c1 + d1)) * inv;
    unsigned int packed = (unsigned int)f2bf(m0) | ((unsigned int)f2bf(m1) << 16);
    *reinterpret_cast<unsigned int*>(meanb + (size_t)node * IND + lane * 2) = packed;
}

// ---------------------------------------------------------------------------
// OLD (small-ws) path gather-mean layer 1: fp32 gather -> A1b cols [0,128).
// ---------------------------------------------------------------------------
__global__ __launch_bounds__(256) void gather1_kernel(
    const float* __restrict__ x, const int* __restrict__ csr,
    const int* __restrict__ rowstart, const int* __restrict__ deg,
    unsigned short* __restrict__ A1b) {
    const int node = blockIdx.x * 4 + (threadIdx.x >> 6);
    const int lane = threadIdx.x & 63;
    const int beg = rowstart[node];
    const int n   = deg[node];
    float2 acc0 = make_float2(0.f, 0.f), acc1 = make_float2(0.f, 0.f);
    int e = 0;
    for (; e + 1 < n; e += 2) {
        int s0 = csr[beg + e];
        int s1 = csr[beg + e + 1];
        float2 v0 = *reinterpret_cast<const float2*>(x + (size_t)s0 * IND + lane * 2);
        float2 v1 = *reinterpret_cast<const float2*>(x + (size_t)s1 * IND + lane * 2);
        acc0.x += v0.x; acc0.y += v0.y;
        acc1.x += v1.x; acc1.y += v1.y;
    }
    if (e < n) {
        int s0 = csr[beg + e];
        float2 v0 = *reinterpret_cast<const float2*>(x + (size_t)s0 * IND + lane * 2);
        acc0.x += v0.x; acc0.y += v0.y;
    }
    const float inv = (n > 0) ? 1.0f / (float)n : 0.0f;
    unsigned int packed = (unsigned int)f2bf((acc0.x + acc1.x) * inv)
                        | ((unsigned int)f2bf((acc0.y + acc1.y) * inv) << 16);
    *reinterpret_cast<unsigned int*>(A1b + (size_t)node * 256 + lane * 2) = packed;
}

// ---------------------------------------------------------------------------
// Layer-1 dense GEMM on MFMA, two-pointer A (mean half / x half).
// ---------------------------------------------------------------------------
__global__ __launch_bounds__(256) void sage1_kernel(
    const unsigned short* __restrict__ Am, int sM,
    const unsigned short* __restrict__ Ax, int sX,
    const unsigned short* __restrict__ Wb,
    const float* __restrict__ b1,
    unsigned short* __restrict__ hb) {
    const int t    = threadIdx.x;
    const int wave = t >> 6;
    const int lane = t & 63;
    const int l15  = lane & 15;
    const int kh   = lane >> 4;              // 0..3
    const int wm   = wave >> 1;              // 0..1
    const int wn   = wave & 1;               // 0..1
    const int row0 = blockIdx.x * 64 + wm * 32;    // 625*64 == 40000 exact
    const int col0 = blockIdx.y * 128 + wn * 64;

    f32x4 acc[2][4];
#pragma unroll
    for (int m = 0; m < 2; ++m)
#pragma unroll
        for (int n = 0; n < 4; ++n)
            acc[m][n] = (f32x4){0.f, 0.f, 0.f, 0.f};

#pragma unroll
    for (int ks = 0; ks < 8; ++ks) {
        const unsigned short* __restrict__ Ab = (ks < 4) ? Am : Ax;
        const int sA = (ks < 4) ? sM : sX;
        const int k0 = (ks & 3) * 32 + kh * 8;
        bf16x8 a[2], b[4];
#pragma unroll
        for (int m = 0; m < 2; ++m)
            a[m] = *reinterpret_cast<const bf16x8*>(
                Ab + (size_t)(row0 + m * 16 + l15) * sA + k0);
#pragma unroll
        for (int n = 0; n < 4; ++n)
            b[n] = *reinterpret_cast<const bf16x8*>(
                Wb + (size_t)(col0 + n * 16 + l15) * 256 + ks * 32 + kh * 8);
#pragma unroll
        for (int m = 0; m < 2; ++m)
#pragma unroll
            for (int n = 0; n < 4; ++n)
                acc[m][n] = __builtin_amdgcn_mfma_f32_16x16x32_bf16(
                    a[m], b[n], acc[m][n], 0, 0, 0);
    }

#pragma unroll
    for (int m = 0; m < 2; ++m) {
        const int r0 = row0 + m * 16 + kh * 4;
#pragma unroll
        for (int n = 0; n < 4; ++n) {
            const int c = col0 + n * 16 + l15;
            const float bias = b1[c];
#pragma unroll
            for (int j = 0; j < 4; ++j)
                hb[(size_t)(r0 + j) * HID + c] =
                    f2bf(fmaxf(acc[m][n][j] + bias, 0.0f));
        }
    }
}

// ---------------------------------------------------------------------------
// Gather-mean layer 2 (bf16 in, f32 accum, bf16 out, 4-edge unroll).
// ---------------------------------------------------------------------------
__global__ __launch_bounds__(256) void gather2_kernel(
    const unsigned short* __restrict__ hb, const int* __restrict__ csr,
    const int* __restrict__ rowstart, const int* __restrict__ deg,
    unsigned short* __restrict__ meanb) {
    const int node = blockIdx.x * 4 + (threadIdx.x >> 6);
    const int lane = threadIdx.x & 63;
    const int beg = rowstart[node];
    const int n   = deg[node];
    const unsigned short* __restrict__ hcol = hb + lane * 4;
    float acc0 = 0.f, acc1 = 0.f, acc2 = 0.f, acc3 = 0.f;
    int e = 0;
    for (; e + 3 < n; e += 4) {
        int s0 = csr[beg + e],     s1 = csr[beg + e + 1];
        int s2 = csr[beg + e + 2], s3 = csr[beg + e + 3];
        ushort4 v0 = *reinterpret_cast<const ushort4*>(hcol + (size_t)s0 * HID);
        ushort4 v1 = *reinterpret_cast<const ushort4*>(hcol + (size_t)s1 * HID);
        ushort4 v2 = *reinterpret_cast<const ushort4*>(hcol + (size_t)s2 * HID);
        ushort4 v3 = *reinterpret_cast<const ushort4*>(hcol + (size_t)s3 * HID);
        acc0 += (bf2f(v0.x) + bf2f(v1.x)) + (bf2f(v2.x) + bf2f(v3.x));
        acc1 += (bf2f(v0.y) + bf2f(v1.y)) + (bf2f(v2.y) + bf2f(v3.y));
        acc2 += (bf2f(v0.z) + bf2f(v1.z)) + (bf2f(v2.z) + bf2f(v3.z));
        acc3 += (bf2f(v0.w) + bf2f(v1.w)) + (bf2f(v2.w) + bf2f(v3.w));
    }
    for (; e < n; ++e) {
        int s0 = csr[beg + e];
        ushort4 v0 = *reinterpret_cast<const ushort4*>(hcol + (size_t)s0 * HID);
        acc0 += bf2f(v0.x); acc1 += bf2f(v0.y);
        acc2 += bf2f(v0.z); acc3 += bf2f(v0.w);
    }
    const float inv = (n > 0) ? 1.0f / (float)n : 0.0f;
    unsigned int lo = (unsigned int)f2bf(acc0 * inv)
                    | ((unsigned int)f2bf(acc1 * inv) << 16);
    unsigned int hi = (unsigned int)f2bf(acc2 * inv)
                    | ((unsigned int)f2bf(acc3 * inv) << 16);
    *reinterpret_cast<uint2*>(meanb + (size_t)node * HID + lane * 4) =
        make_uint2(lo, hi);
}

// ---------------------------------------------------------------------------
// Layer-2 dense GEMM on MFMA + in-register log_softmax.
// ---------------------------------------------------------------------------
__global__ __launch_bounds__(256) void sage2_kernel(
    const unsigned short* __restrict__ hb,
    const unsigned short* __restrict__ meanb,
    const unsigned short* __restrict__ Wb,
    const float* __restrict__ b2,
    float* __restrict__ out) {
    const int t    = threadIdx.x;
    const int wave = t >> 6;
    const int lane = t & 63;
    const int l15  = lane & 15;
    const int kh   = lane >> 4;
    const int row0 = blockIdx.x * 64 + wave * 16;
    const int arow = min(row0 + l15, N3 - 1);   // clamp loads; stores guarded

    f32x4 acc[4];
#pragma unroll
    for (int n = 0; n < 4; ++n) acc[n] = (f32x4){0.f, 0.f, 0.f, 0.f};

#pragma unroll
    for (int half = 0; half < 2; ++half) {
        const unsigned short* __restrict__ A = half ? hb : meanb;
#pragma unroll
        for (int ks = 0; ks < 8; ++ks) {
            const int k0 = ks * 32 + kh * 8;
            bf16x8 a = *reinterpret_cast<const bf16x8*>(
                A + (size_t)arow * HID + k0);
            bf16x8 b[4];
#pragma unroll
            for (int n = 0; n < 4; ++n)
                b[n] = *reinterpret_cast<const bf16x8*>(
                    Wb + (size_t)(n * 16 + l15) * 512 + half * 256 + k0);
#pragma unroll
            for (int n = 0; n < 4; ++n)
                acc[n] = __builtin_amdgcn_mfma_f32_16x16x32_bf16(
                    a, b[n], acc[n], 0, 0, 0);
        }
    }

    float v[4][4];
#pragma unroll
    for (int n = 0; n < 4; ++n) {
        const float bn = b2[n * 16 + l15];
#pragma unroll
        for (int j = 0; j < 4; ++j) v[n][j] = acc[n][j] + bn;
    }

#pragma unroll
    for (int j = 0; j < 4; ++j) {
        float mx = fmaxf(fmaxf(v[0][j], v[1][j]), fmaxf(v[2][j], v[3][j]));
#pragma unroll
        for (int o = 1; o <= 8; o <<= 1) mx = fmaxf(mx, __shfl_xor(mx, o));
        float sm = 0.f;
#pragma unroll
        for (int n = 0; n < 4; ++n) sm += __expf(v[n][j] - mx);
#pragma unroll
        for (int o = 1; o <= 8; o <<= 1) sm += __shfl_xor(sm, o);
        const float lse = mx + __logf(sm);
        const int r = row0 + kh * 4 + j;
        if (r < N3) {
#pragma unroll
            for (int n = 0; n < 4; ++n)
                out[(size_t)r * OUTD + n * 16 + l15] = v[n][j] - lse;
        }
    }
}

// ---------------------------------------------------------------------------
extern "C" void kernel_launch(void* const* d_in, const int* in_sizes, int n_in,
                              void* d_out, int out_size, void* d_ws, size_t ws_size,
                              hipStream_t stream) {
    const float* x    = (const float*)d_in[0];
    const int*   src1 = (const int*)d_in[1];
    const int*   dst1 = (const int*)d_in[2];
    const int*   src2 = (const int*)d_in[3];
    const int*   dst2 = (const int*)d_in[4];
    const float* W1l  = (const float*)d_in[7];
    const float* W1r  = (const float*)d_in[8];
    const float* b1   = (const float*)d_in[9];
    const float* W2l  = (const float*)d_in[10];
    const float* W2r  = (const float*)d_in[11];
    const float* b2   = (const float*)d_in[12];
    float* out = (float*)d_out;

    const int E1 = in_sizes[1];
    const int E2 = in_sizes[3];

    static constexpr size_t NEED_NEW = 85916608;
    const bool big = ws_size >= NEED_NEW;

    char* ws = (char*)d_ws;
    unsigned short *mean1b, *mean2b, *hb, *xb = nullptr, *A1b = nullptr;
    unsigned short *W2b, *Wb1;
    int *csr1, *csr2, *deg1, *cursor1, *deg2, *cursor2, *rowstart1, *rowstart2;
    char* z0;   // start of the contiguous {deg1,cursor1,deg2,cursor2} block

    if (big) {
        mean1b   = (unsigned short*)(ws + 0);           // 10,240,000
        mean2b   = (unsigned short*)(ws + 0);           // aliases (5.12 MB)
        hb       = (unsigned short*)(ws + 10240000);    // 20,480,000
        xb       = (unsigned short*)(ws + 30720000);    // 51,200,000
        csr1     = (int*)(ws + 81920000);               //  2,560,000
        csr2     = (int*)(ws + 84480000);               //    640,000
        deg1     = (int*)(ws + 85120000);               //    160,000
        cursor1  = (int*)(ws + 85280000);               //    160,000
        deg2     = (int*)(ws + 85440000);               //     40,000
        cursor2  = (int*)(ws + 85480000);               //     40,000
        rowstart1= (int*)(ws + 85520000);
        rowstart2= (int*)(ws + 85680000);
        W2b      = (unsigned short*)(ws + 85720000);
        Wb1      = (unsigned short*)(ws + 85785536);    // end 85,916,608
        z0 = ws + 85120000;
    } else {
        A1b      = (unsigned short*)(ws + 0);           // 20,480,000
        mean1b   = nullptr;
        mean2b   = (unsigned short*)(ws + 0);
        hb       = (unsigned short*)(ws + 20480000);    // 20,480,000
        csr1     = (int*)(ws + 40960000);               //  2,560,000
        csr2     = (int*)(ws + 43520000);               //    640,000
        deg1     = (int*)(ws + 44160000);
        cursor1  = (int*)(ws + 44320000);
        deg2     = (int*)(ws + 44480000);
        cursor2  = (int*)(ws + 44520000);
        rowstart1= (int*)(ws + 44560000);
        rowstart2= (int*)(ws + 44720000);
        W2b      = (unsigned short*)(ws + 44760000);
        Wb1      = (unsigned short*)(ws + 44825536);    // end 44,956,608
        z0 = ws + 44160000;
    }

    // ---- fused prep: zero + weight converts + x convert (1 launch) ----
    {
        const int NX = big ? NX_BIG : NX_SMALL;
        const int total = NX + NZ4 + NW1g + NW2g;
        prep_kernel<<<(total + 255) / 256, 256, 0, stream>>>(
            x, big ? xb : A1b, (int)big, (int4*)z0,
            W1l, W1r, Wb1, W2l, W2r, W2b);
    }

    // ---- fused CSR build: hist -> single-block scan -> fill (3 launches) ----
    {
        int tot = E1 + E2;
        hist_both_kernel<<<(tot + 255) / 256, 256, 0, stream>>>(
            dst1, E1, dst2, E2, deg1, deg2);
        scan_fused_kernel<<<1, 1024, 0, stream>>>(deg1, rowstart1,
                                                  deg2, rowstart2);
        fill_both_kernel<<<(tot + 255) / 256, 256, 0, stream>>>(
            src1, dst1, E1, rowstart1, cursor1, csr1,
            src2, dst2, E2, rowstart2, cursor2, csr2);
    }

    // ---- layer 1: gather-mean + MFMA dense ----
    if (big) {
        gather1b_kernel<<<N2 / 4, 256, 0, stream>>>(xb, csr1, rowstart1, deg1,
                                                    mean1b);
        dim3 grid(N2 / 64, HID / 128);
        sage1_kernel<<<grid, 256, 0, stream>>>(mean1b, IND, xb, IND, Wb1, b1, hb);
    } else {
        gather1_kernel<<<N2 / 4, 256, 0, stream>>>(x, csr1, rowstart1, deg1, A1b);
        dim3 grid(N2 / 64, HID / 128);
        sage1_kernel<<<grid, 256, 0, stream>>>(A1b, HID, A1b + 128, HID, Wb1,
                                               b1, hb);
    }

    // ---- layer 2: gather-mean + MFMA dense + log_softmax ----
    gather2_kernel<<<N3 / 4, 256, 0, stream>>>(hb, csr2, rowstart2, deg2, mean2b);
    sage2_kernel<<<(N3 + 63) / 64, 256, 0, stream>>>(hb, mean2b, W2b, b2, out);
}